// Round 1
// baseline (351.526 us; speedup 1.0000x reference)
//
#include <hip/hip_runtime.h>
#include <math.h>

#define BB 8
#define NN 4096
#define DD 2048

typedef __attribute__((ext_vector_type(8))) short bf16x8;
typedef __attribute__((ext_vector_type(4))) float f32x4;
typedef const __attribute__((address_space(1))) unsigned gu32;
typedef __attribute__((address_space(3))) unsigned lu32;

// fp32 -> bf16 round-to-nearest-even (inputs are finite randoms; no NaN path)
__device__ __forceinline__ short f2bf(float f) {
    unsigned int u = __float_as_uint(f);
    unsigned int r = (u + 0x7fffu + ((u >> 16) & 1u)) >> 16;
    return (short)r;
}
__device__ __forceinline__ float bf2f(short s) {
    return __uint_as_float(((unsigned int)(unsigned short)s) << 16);
}

// ---- K0: pack V (2048x64 fp32) into MFMA B-frag order ----
// Vp[((w*64+kc)*64 + lane)*8 + j] = bf16(V[kc*32 + (lane>>4)*8 + j][w*16 + (lane&15)])
__global__ __launch_bounds__(256) void k_pack_v(const float* __restrict__ V,
                                                short* __restrict__ Vp) {
    int e = blockIdx.x * 256 + threadIdx.x;    // 0..16383
    int lane = e & 63, kc = (e >> 6) & 63, w = e >> 12;
    int q = lane >> 4, mm = lane & 15;
    int kb = kc * 32 + q * 8, l = w * 16 + mm;
    bf16x8 o;
    #pragma unroll
    for (int j = 0; j < 8; j++) o[j] = f2bf(V[(size_t)(kb + j) * 64 + l]);
    *(bf16x8*)(Vp + (size_t)e * 8) = o;
}

// ---- K1: fused dis-GEMM + block-local online-softmax + e-weighted q-dots ----
// Staging: global fp32 -> (global_load_lds, deep async queue) -> Fbuf rotating
// 2-row fp32 buffer -> f2bf + XOR-swizzle -> Xs. Each wave owns a 512-float
// quarter of every row: no cross-wave deps, no barriers in the staging loop.
// Counted vmcnt: per wave, 2 rows (4 KiB) stay in flight; 2 blk/CU -> 32 KiB/CU.
__global__ __launch_bounds__(256, 2) void k_fused(
        const float* __restrict__ x, const int* __restrict__ tn_p,
        const short* __restrict__ Vp, const float* __restrict__ W,
        const float* __restrict__ fc_w,
        float* __restrict__ dis, float* __restrict__ mblk,
        float* __restrict__ lblk, float* __restrict__ qblk) {
    __shared__ __align__(16) short Xs[16 * 2048];   // 64 KiB bf16 tile
    __shared__ __align__(16) float Fbuf[2 * 2048];  // 16 KiB fp32 row x2 (staging)
    // 80 KiB total -> exactly 2 blocks/CU

    const int tid = threadIdx.x;
    const int blk = blockIdx.x;
    const int b  = blk >> 8;
    const int n0 = (blk & 255) << 4;
    const int tn = tn_p[b];
    if (n0 >= tn) return;             // fully-masked tile

    const int lane = tid & 63, w = tid >> 6;
    const int mm = lane & 15, q = lane >> 4;

    const float* xrow = x + ((size_t)(b * NN + n0)) * DD;

// issue one row-quarter (512 floats) as 2x global_load_lds dwordx4 (1 KiB each)
#define ISSUE(r) do { \
    const float* s0_ = xrow + (size_t)(r) * DD + (w << 9) + (lane << 2); \
    float* d0_ = Fbuf + (((r) & 1) << 11) + (w << 9); \
    __builtin_amdgcn_global_load_lds((gu32*)(s0_),       (lu32*)(d0_),       16, 0, 0); \
    __builtin_amdgcn_global_load_lds((gu32*)(s0_ + 256), (lu32*)(d0_ + 256), 16, 0, 0); \
} while (0)

// wait row r's loads (counted vmcnt), convert quarter to bf16 into swizzled Xs,
// then refill the buffer slot with row r+2
#define CONV(r, VM) do { \
    asm volatile("s_waitcnt vmcnt(" #VM ")" ::: "memory"); \
    const float* f_ = Fbuf + (((r) & 1) << 11) + (w << 9) + (lane << 3); \
    f32x4 lo = *(const f32x4*)f_; \
    f32x4 hi = *(const f32x4*)(f_ + 4); \
    bf16x8 o_; \
    o_[0] = f2bf(lo.x); o_[1] = f2bf(lo.y); o_[2] = f2bf(lo.z); o_[3] = f2bf(lo.w); \
    o_[4] = f2bf(hi.x); o_[5] = f2bf(hi.y); o_[6] = f2bf(hi.z); o_[7] = f2bf(hi.w); \
    int c_ = (w << 6) + lane; \
    *(bf16x8*)&Xs[(r) * 2048 + ((c_ ^ ((r) & 7)) << 3)] = o_; \
    if ((r) + 2 < 16) ISSUE((r) + 2); \
} while (0)

    ISSUE(0); ISSUE(1);               // rows 0,1 in flight (4 vmem/wave)
    asm volatile("" ::: "memory");    // pin: prefetch below cannot hoist above
    // B-frag prefetch + W load: exactly 5 vmem loads, counted in the waits
    const bf16x8* vpv = (const bf16x8*)Vp + ((size_t)w << 12) + lane;
    bf16x8 bvr[4];
    #pragma unroll
    for (int j = 0; j < 4; j++) bvr[j] = vpv[j << 6];
    const float wl = W[w * 16 + mm];
    // outstanding: [r0(2) r1(2) P(5)]
    CONV(0, 7);  CONV(1, 7);          // retire r0 / r1, keep P+next in flight
    CONV(2, 2);  CONV(3, 2);  CONV(4, 2);  CONV(5, 2);
    CONV(6, 2);  CONV(7, 2);  CONV(8, 2);  CONV(9, 2);
    CONV(10, 2); CONV(11, 2); CONV(12, 2); CONV(13, 2);
    CONV(14, 2); CONV(15, 0);
#undef CONV
#undef ISSUE

    __syncthreads();

    // ---- GEMM: wave w -> cols 16w..16w+15; 4-deep B prefetch pipeline ----
    const int arow = mm * 2048;
    const int msw = mm & 7;
    f32x4 acc = {0.f, 0.f, 0.f, 0.f};
    #pragma unroll
    for (int kc = 0; kc < 64; kc += 4) {
        bf16x8 cur0 = bvr[0], cur1 = bvr[1], cur2 = bvr[2], cur3 = bvr[3];
        if (kc + 4 < 64) {
            #pragma unroll
            for (int j = 0; j < 4; j++) bvr[j] = vpv[(kc + 4 + j) << 6];
        }
        bf16x8 a0 = *(const bf16x8*)&Xs[arow + ((((kc + 0) * 4 + q) ^ msw) << 3)];
        acc = __builtin_amdgcn_mfma_f32_16x16x32_bf16(a0, cur0, acc, 0, 0, 0);
        bf16x8 a1 = *(const bf16x8*)&Xs[arow + ((((kc + 1) * 4 + q) ^ msw) << 3)];
        acc = __builtin_amdgcn_mfma_f32_16x16x32_bf16(a1, cur1, acc, 0, 0, 0);
        bf16x8 a2 = *(const bf16x8*)&Xs[arow + ((((kc + 2) * 4 + q) ^ msw) << 3)];
        acc = __builtin_amdgcn_mfma_f32_16x16x32_bf16(a2, cur2, acc, 0, 0, 0);
        bf16x8 a3 = *(const bf16x8*)&Xs[arow + ((((kc + 3) * 4 + q) ^ msw) << 3)];
        acc = __builtin_amdgcn_mfma_f32_16x16x32_bf16(a3, cur3, acc, 0, 0, 0);
    }

    // fc_w fragment loads early (overlap L2 latency with epilogue reductions)
    const float4* w0p = (const float4*)fc_w + tid * 2;
    const float4* w1p = (const float4*)(fc_w + DD) + tid * 2;
    float4 wa = w0p[0], wb = w0p[1], wc = w1p[0], wd = w1p[1];

    // staging buffer is dead from here: alias the tiny reduce scratch into it
    float* dp  = Fbuf;        // 64 floats: per-wave partial col-sums
    float* ers = Fbuf + 64;   // 16 floats: tile softmax numerators

    // ---- epilogue: dis rows; C layout col=lane&15, row=(lane>>4)*4+reg ----
    #pragma unroll
    for (int r = 0; r < 4; r++) {
        float p = tanhf(acc[r]) * wl;
        p += __shfl_xor(p, 1, 64);
        p += __shfl_xor(p, 2, 64);
        p += __shfl_xor(p, 4, 64);
        p += __shfl_xor(p, 8, 64);
        if (mm == 0) dp[w * 16 + q * 4 + r] = p;   // per-wave partial col-sum
    }
    __syncthreads();

    if (w == 0) {
        float d = (dp[mm] + dp[16 + mm] + dp[32 + mm] + dp[48 + mm]) * 0.125f;
        int n = n0 + mm;
        if (n >= tn) d = -1e20f;                    // in-tile masked rows
        if (lane < 16) dis[b * NN + n] = d;
        float mx = d;
        mx = fmaxf(mx, __shfl_xor(mx, 1, 64));
        mx = fmaxf(mx, __shfl_xor(mx, 2, 64));
        mx = fmaxf(mx, __shfl_xor(mx, 4, 64));
        mx = fmaxf(mx, __shfl_xor(mx, 8, 64));
        float e = expf(d - mx);                     // masked -> 0
        float ls = e;
        ls += __shfl_xor(ls, 1, 64);
        ls += __shfl_xor(ls, 2, 64);
        ls += __shfl_xor(ls, 4, 64);
        ls += __shfl_xor(ls, 8, 64);
        if (lane < 16) ers[lane] = e;
        if (lane == 0) { mblk[blk] = mx; lblk[blk] = ls; }
    }
    __syncthreads();

    // ---- weighted partial for chunk d = 8*tid..8*tid+7, dotted with fc_w ----
    float facc[8];
    #pragma unroll
    for (int u = 0; u < 8; u++) facc[u] = 0.f;
    #pragma unroll
    for (int r = 0; r < 16; r++) {
        bf16x8 sv = *(const bf16x8*)&Xs[r * 2048 + ((tid ^ (r & 7)) << 3)];
        float e = ers[r];                           // LDS broadcast (free)
        #pragma unroll
        for (int u = 0; u < 8; u++) facc[u] = fmaf(e, bf2f(sv[u]), facc[u]);
    }
    float q0 = facc[0] * wa.x + facc[1] * wa.y + facc[2] * wa.z + facc[3] * wa.w +
               facc[4] * wb.x + facc[5] * wb.y + facc[6] * wb.z + facc[7] * wb.w;
    float q1 = facc[0] * wc.x + facc[1] * wc.y + facc[2] * wc.z + facc[3] * wc.w +
               facc[4] * wd.x + facc[5] * wd.y + facc[6] * wd.z + facc[7] * wd.w;
    #pragma unroll
    for (int o = 32; o >= 1; o >>= 1) {
        q0 += __shfl_xor(q0, o, 64);
        q1 += __shfl_xor(q1, o, 64);
    }
    if (lane == 0) {   // per-wave slot: no atomics, no zero-init needed
        qblk[blk * 8 + w * 2 + 0] = q0;
        qblk[blk * 8 + w * 2 + 1] = q1;
    }
}

// ---- K2: per-batch: combine m/l -> M,L ; soft_assign ; logits -> cls ----
// grid 32 = 8 batches x 4 slices; every slice recomputes M/L (cheap), slice 0 -> cls
__global__ __launch_bounds__(256) void k_final(
        const float* __restrict__ dis, const int* __restrict__ tn_p,
        const float* __restrict__ mblk, const float* __restrict__ lblk,
        const float* __restrict__ qblk, const float* __restrict__ fc_b,
        float* __restrict__ soft, float* __restrict__ cls) {
    __shared__ float red[4];
    __shared__ float r3[3][4];
    __shared__ float bc;
    const int b = blockIdx.x >> 2, s = blockIdx.x & 3, t = threadIdx.x;
    const int tn = tn_p[b];
    const int nvb = (tn + 15) >> 4;             // valid tiles, 1..256

    float mt = (t < nvb) ? mblk[b * 256 + t] : -3.4e38f;
    float mx = mt;
    #pragma unroll
    for (int o = 32; o >= 1; o >>= 1) mx = fmaxf(mx, __shfl_xor(mx, o, 64));
    if ((t & 63) == 0) red[t >> 6] = mx;
    __syncthreads();
    if (t == 0) bc = fmaxf(fmaxf(red[0], red[1]), fmaxf(red[2], red[3]));
    __syncthreads();
    const float M = bc;

    float sc = (t < nvb) ? expf(mt - M) : 0.f;
    float ls = (t < nvb) ? sc * lblk[b * 256 + t] : 0.f;
    float l0 = 0.f, l1 = 0.f;
    if (t < nvb) {
        const float* qp = qblk + (size_t)(b * 256 + t) * 8;
        l0 = sc * (qp[0] + qp[2] + qp[4] + qp[6]);
        l1 = sc * (qp[1] + qp[3] + qp[5] + qp[7]);
    }
    #pragma unroll
    for (int o = 32; o >= 1; o >>= 1) {
        ls += __shfl_xor(ls, o, 64);
        l0 += __shfl_xor(l0, o, 64);
        l1 += __shfl_xor(l1, o, 64);
    }
    if ((t & 63) == 0) {
        r3[0][t >> 6] = ls; r3[1][t >> 6] = l0; r3[2][t >> 6] = l1;
    }
    __syncthreads();
    if (t == 0) {
        float L  = r3[0][0] + r3[0][1] + r3[0][2] + r3[0][3];
        bc = 1.f / L;
        if (s == 0) {
            float Q0 = r3[1][0] + r3[1][1] + r3[1][2] + r3[1][3];
            float Q1 = r3[2][0] + r3[2][1] + r3[2][2] + r3[2][3];
            float L0 = Q0 / L + fc_b[0];
            float L1 = Q1 / L + fc_b[1];
            float mm2 = fmaxf(L0, L1);
            float e0 = expf(L0 - mm2), e1 = expf(L1 - mm2);
            float inv = 1.f / (e0 + e1);
            cls[b * 2 + 0] = e0 * inv;
            cls[b * 2 + 1] = e1 * inv;
        }
    }
    __syncthreads();
    const float iL = bc;

    // slice s covers 1024 elements = 256 float4s -> one per thread
    const int i = s * 256 + t;                  // float4 index within batch
    const int n = i * 4;
    float4 dv = ((const float4*)(dis + (size_t)b * NN))[i];
    float4 o;
    o.x = (n + 0 < tn) ? expf(dv.x - M) * iL : 0.f;
    o.y = (n + 1 < tn) ? expf(dv.y - M) * iL : 0.f;
    o.z = (n + 2 < tn) ? expf(dv.z - M) * iL : 0.f;
    o.w = (n + 3 < tn) ? expf(dv.w - M) * iL : 0.f;
    ((float4*)(soft + (size_t)b * NN))[i] = o;
}

extern "C" void kernel_launch(void* const* d_in, const int* in_sizes, int n_in,
                              void* d_out, int out_size, void* d_ws, size_t ws_size,
                              hipStream_t stream) {
    (void)in_sizes; (void)n_in; (void)out_size; (void)ws_size;
    const float* x        = (const float*)d_in[0];
    const int*   true_num = (const int*)d_in[1];
    const float* V        = (const float*)d_in[2];
    const float* W        = (const float*)d_in[3];
    const float* fc_w     = (const float*)d_in[4];
    const float* fc_b     = (const float*)d_in[5];

    float* out  = (float*)d_out;
    float* cls  = out;                     // B*NCLS = 16
    float* soft = out + BB * 2;            // B*N = 32768

    float* dis   = (float*)d_ws;                 // 32768
    float* mblk  = dis + (size_t)BB * NN;        // 2048
    float* lblk  = mblk + 2048;                  // 2048
    float* qblk  = lblk + 2048;                  // 2048*8
    short* Vp    = (short*)(qblk + (size_t)2048 * 8);  // 4*64*64*8 bf16 = 256 KiB

    k_pack_v<<<64, 256, 0, stream>>>(V, Vp);
    k_fused<<<2048, 256, 0, stream>>>(x, true_num, Vp, W, fc_w,
                                      dis, mblk, lblk, qblk);
    k_final<<<32, 256, 0, stream>>>(dis, true_num, mblk, lblk, qblk, fc_b,
                                    soft, cls);
}

// Round 2
// 336.488 us; speedup vs baseline: 1.0447x; 1.0447x over previous
//
#include <hip/hip_runtime.h>
#include <math.h>

#define BB 8
#define NN 4096
#define DD 2048

typedef __attribute__((ext_vector_type(8))) short bf16x8;
typedef __attribute__((ext_vector_type(4))) float f32x4;

// fp32 -> bf16 round-to-nearest-even (inputs are finite randoms; no NaN path)
__device__ __forceinline__ short f2bf(float f) {
    unsigned int u = __float_as_uint(f);
    unsigned int r = (u + 0x7fffu + ((u >> 16) & 1u)) >> 16;
    return (short)r;
}
__device__ __forceinline__ float bf2f(short s) {
    return __uint_as_float(((unsigned int)(unsigned short)s) << 16);
}

// ---- K0: pack V (2048x64 fp32) into MFMA B-frag order ----
// Vp[((w*64+kc)*64 + lane)*8 + j] = bf16(V[kc*32 + (lane>>4)*8 + j][w*16 + (lane&15)])
__global__ __launch_bounds__(256) void k_pack_v(const float* __restrict__ V,
                                                short* __restrict__ Vp) {
    int e = blockIdx.x * 256 + threadIdx.x;    // 0..16383
    int lane = e & 63, kc = (e >> 6) & 63, w = e >> 12;
    int q = lane >> 4, mm = lane & 15;
    int kb = kc * 32 + q * 8, l = w * 16 + mm;
    bf16x8 o;
    #pragma unroll
    for (int j = 0; j < 8; j++) o[j] = f2bf(V[(size_t)(kb + j) * 64 + l]);
    *(bf16x8*)(Vp + (size_t)e * 8) = o;
}

// ---- K1: fused dis-GEMM + block-local online-softmax + e-weighted q-dots ----
// 512 threads (8 waves), 2 blocks/CU -> 4 waves/SIMD (2x round-0 occupancy).
// Split-K GEMM: waves 0-3 cols, K-low half; waves 4-7 same cols, K-high half.
// K-halves combined in LDS BEFORE tanh (tanh of a K-partial is wrong).
// Staging: register-staged nontemporal float4 (round-0 proven path), one full
// row per unrolled iteration, 8 loads/wave in flight; 16 waves/CU issuing.
__global__ __launch_bounds__(512, 4) void k_fused(
        const float* __restrict__ x, const int* __restrict__ tn_p,
        const short* __restrict__ Vp, const float* __restrict__ W,
        const float* __restrict__ fc_w,
        float* __restrict__ dis, float* __restrict__ mblk,
        float* __restrict__ lblk, float* __restrict__ qblk) {
    __shared__ __align__(16) short Xs[16 * 2048];    // 64 KiB bf16 tile
    __shared__ __align__(16) float comb[4 * 64 * 4]; // 4 KiB K-high partials
    __shared__ float dp[64];
    __shared__ float ers[16];
    // ~70 KiB total -> 2 blocks/CU

    const int tid = threadIdx.x;          // 0..511
    const int blk = blockIdx.x;
    const int b  = blk >> 8;
    const int n0 = (blk & 255) << 4;
    const int tn = tn_p[b];
    if (n0 >= tn) return;                 // fully-masked tile (block-uniform)

    const int lane = tid & 63, w = tid >> 6;   // w 0..7
    const int wc = w & 3, wk = w >> 2;         // col-group, K-half
    const int mm = lane & 15, q = lane >> 4;

    // ---- stage: 16 rows x 2048 fp32 -> bf16 LDS (nontemporal: x read once) ----
    // iteration r: whole block loads row r (512 float4 = 8 KiB), coalesced
    const f32x4* xsrc = (const f32x4*)(x + ((size_t)(b * NN + n0)) * DD);
    const int cch = tid >> 1, hh = tid & 1;    // 16B chunk, half
    #pragma unroll 8
    for (int r = 0; r < 16; r++) {
        f32x4 v = __builtin_nontemporal_load(&xsrc[(size_t)r * 512 + tid]);
        int sc = cch ^ (r & 7);                // swizzle
        short4 s;
        s.x = f2bf(v.x); s.y = f2bf(v.y); s.z = f2bf(v.z); s.w = f2bf(v.w);
        *(short4*)&Xs[r * 2048 + sc * 8 + hh * 4] = s;
    }

    // B-frag prefetch (independent of LDS) + W load, issued under staging drain
    const bf16x8* vpv = (const bf16x8*)Vp + ((size_t)wc << 12) + lane;
    const int kbase = wk << 5;                 // 0 or 32
    bf16x8 bvr[4];
    #pragma unroll
    for (int j = 0; j < 4; j++) bvr[j] = vpv[(kbase + j) << 6];
    const float wl = W[wc * 16 + mm];

    __syncthreads();

    // ---- GEMM: wave -> cols 16wc..16wc+15, K-half wk; 4-deep B prefetch ----
    const int arow = mm * 2048;
    const int msw = mm & 7;
    f32x4 acc = {0.f, 0.f, 0.f, 0.f};
    #pragma unroll
    for (int kc = 0; kc < 32; kc += 4) {
        bf16x8 cur0 = bvr[0], cur1 = bvr[1], cur2 = bvr[2], cur3 = bvr[3];
        if (kc + 4 < 32) {
            #pragma unroll
            for (int j = 0; j < 4; j++) bvr[j] = vpv[(kbase + kc + 4 + j) << 6];
        }
        bf16x8 a0 = *(const bf16x8*)&Xs[arow + ((((kbase + kc + 0) * 4 + q) ^ msw) << 3)];
        acc = __builtin_amdgcn_mfma_f32_16x16x32_bf16(a0, cur0, acc, 0, 0, 0);
        bf16x8 a1 = *(const bf16x8*)&Xs[arow + ((((kbase + kc + 1) * 4 + q) ^ msw) << 3)];
        acc = __builtin_amdgcn_mfma_f32_16x16x32_bf16(a1, cur1, acc, 0, 0, 0);
        bf16x8 a2 = *(const bf16x8*)&Xs[arow + ((((kbase + kc + 2) * 4 + q) ^ msw) << 3)];
        acc = __builtin_amdgcn_mfma_f32_16x16x32_bf16(a2, cur2, acc, 0, 0, 0);
        bf16x8 a3 = *(const bf16x8*)&Xs[arow + ((((kbase + kc + 3) * 4 + q) ^ msw) << 3)];
        acc = __builtin_amdgcn_mfma_f32_16x16x32_bf16(a3, cur3, acc, 0, 0, 0);
    }

    // fc_w fragment loads early (overlap L2 latency with combine/reductions)
    const float4 wa = ((const float4*)fc_w)[tid];          // row 0, 4 floats
    const float4 wb = ((const float4*)(fc_w + DD))[tid];   // row 1, 4 floats

    // ---- combine K-halves before tanh ----
    if (wk == 1) *(f32x4*)&comb[(wc * 64 + lane) * 4] = acc;
    __syncthreads();

    // ---- epilogue: dis rows; C layout col=lane&15, row=(lane>>4)*4+reg ----
    if (wk == 0) {
        f32x4 o = *(const f32x4*)&comb[(wc * 64 + lane) * 4];
        acc += o;
        #pragma unroll
        for (int r = 0; r < 4; r++) {
            float p = tanhf(acc[r]) * wl;
            p += __shfl_xor(p, 1, 64);
            p += __shfl_xor(p, 2, 64);
            p += __shfl_xor(p, 4, 64);
            p += __shfl_xor(p, 8, 64);
            if (mm == 0) dp[wc * 16 + q * 4 + r] = p;   // per-colgroup partial
        }
    }
    __syncthreads();

    if (w == 0) {
        float d = (dp[mm] + dp[16 + mm] + dp[32 + mm] + dp[48 + mm]) * 0.125f;
        int n = n0 + mm;
        if (n >= tn) d = -1e20f;                    // in-tile masked rows
        if (lane < 16) dis[b * NN + n] = d;
        float mx = d;
        mx = fmaxf(mx, __shfl_xor(mx, 1, 64));
        mx = fmaxf(mx, __shfl_xor(mx, 2, 64));
        mx = fmaxf(mx, __shfl_xor(mx, 4, 64));
        mx = fmaxf(mx, __shfl_xor(mx, 8, 64));
        float e = expf(d - mx);                     // masked -> 0
        float ls = e;
        ls += __shfl_xor(ls, 1, 64);
        ls += __shfl_xor(ls, 2, 64);
        ls += __shfl_xor(ls, 4, 64);
        ls += __shfl_xor(ls, 8, 64);
        if (lane < 16) ers[lane] = e;
        if (lane == 0) { mblk[blk] = mx; lblk[blk] = ls; }
    }
    __syncthreads();

    // ---- weighted partial for chunk d = 4*tid..4*tid+3, dotted with fc_w ----
    float facc[4] = {0.f, 0.f, 0.f, 0.f};
    #pragma unroll
    for (int r = 0; r < 16; r++) {
        short4 sv = *(const short4*)&Xs[r * 2048 + ((cch ^ (r & 7)) << 3) + hh * 4];
        float e = ers[r];                           // LDS broadcast (free)
        facc[0] = fmaf(e, bf2f(sv.x), facc[0]);
        facc[1] = fmaf(e, bf2f(sv.y), facc[1]);
        facc[2] = fmaf(e, bf2f(sv.z), facc[2]);
        facc[3] = fmaf(e, bf2f(sv.w), facc[3]);
    }
    float q0 = facc[0] * wa.x + facc[1] * wa.y + facc[2] * wa.z + facc[3] * wa.w;
    float q1 = facc[0] * wb.x + facc[1] * wb.y + facc[2] * wb.z + facc[3] * wb.w;
    #pragma unroll
    for (int o = 32; o >= 1; o >>= 1) {
        q0 += __shfl_xor(q0, o, 64);
        q1 += __shfl_xor(q1, o, 64);
    }
    if (lane == 0) {   // per-wave slot: no atomics, no zero-init needed
        qblk[blk * 16 + w * 2 + 0] = q0;
        qblk[blk * 16 + w * 2 + 1] = q1;
    }
}

// ---- K2: per-batch: combine m/l -> M,L ; soft_assign ; logits -> cls ----
// grid 32 = 8 batches x 4 slices; every slice recomputes M/L (cheap), slice 0 -> cls
__global__ __launch_bounds__(256) void k_final(
        const float* __restrict__ dis, const int* __restrict__ tn_p,
        const float* __restrict__ mblk, const float* __restrict__ lblk,
        const float* __restrict__ qblk, const float* __restrict__ fc_b,
        float* __restrict__ soft, float* __restrict__ cls) {
    __shared__ float red[4];
    __shared__ float r3[3][4];
    __shared__ float bc;
    const int b = blockIdx.x >> 2, s = blockIdx.x & 3, t = threadIdx.x;
    const int tn = tn_p[b];
    const int nvb = (tn + 15) >> 4;             // valid tiles, 1..256

    float mt = (t < nvb) ? mblk[b * 256 + t] : -3.4e38f;
    float mx = mt;
    #pragma unroll
    for (int o = 32; o >= 1; o >>= 1) mx = fmaxf(mx, __shfl_xor(mx, o, 64));
    if ((t & 63) == 0) red[t >> 6] = mx;
    __syncthreads();
    if (t == 0) bc = fmaxf(fmaxf(red[0], red[1]), fmaxf(red[2], red[3]));
    __syncthreads();
    const float M = bc;

    float sc = (t < nvb) ? expf(mt - M) : 0.f;
    float ls = (t < nvb) ? sc * lblk[b * 256 + t] : 0.f;
    float l0 = 0.f, l1 = 0.f;
    if (t < nvb) {
        const float* qp = qblk + (size_t)(b * 256 + t) * 16;
        l0 = sc * (qp[0] + qp[2] + qp[4] + qp[6] + qp[8] + qp[10] + qp[12] + qp[14]);
        l1 = sc * (qp[1] + qp[3] + qp[5] + qp[7] + qp[9] + qp[11] + qp[13] + qp[15]);
    }
    #pragma unroll
    for (int o = 32; o >= 1; o >>= 1) {
        ls += __shfl_xor(ls, o, 64);
        l0 += __shfl_xor(l0, o, 64);
        l1 += __shfl_xor(l1, o, 64);
    }
    if ((t & 63) == 0) {
        r3[0][t >> 6] = ls; r3[1][t >> 6] = l0; r3[2][t >> 6] = l1;
    }
    __syncthreads();
    if (t == 0) {
        float L  = r3[0][0] + r3[0][1] + r3[0][2] + r3[0][3];
        bc = 1.f / L;
        if (s == 0) {
            float Q0 = r3[1][0] + r3[1][1] + r3[1][2] + r3[1][3];
            float Q1 = r3[2][0] + r3[2][1] + r3[2][2] + r3[2][3];
            float L0 = Q0 / L + fc_b[0];
            float L1 = Q1 / L + fc_b[1];
            float mm2 = fmaxf(L0, L1);
            float e0 = expf(L0 - mm2), e1 = expf(L1 - mm2);
            float inv = 1.f / (e0 + e1);
            cls[b * 2 + 0] = e0 * inv;
            cls[b * 2 + 1] = e1 * inv;
        }
    }
    __syncthreads();
    const float iL = bc;

    // slice s covers 1024 elements = 256 float4s -> one per thread
    const int i = s * 256 + t;                  // float4 index within batch
    const int n = i * 4;
    float4 dv = ((const float4*)(dis + (size_t)b * NN))[i];
    float4 o;
    o.x = (n + 0 < tn) ? expf(dv.x - M) * iL : 0.f;
    o.y = (n + 1 < tn) ? expf(dv.y - M) * iL : 0.f;
    o.z = (n + 2 < tn) ? expf(dv.z - M) * iL : 0.f;
    o.w = (n + 3 < tn) ? expf(dv.w - M) * iL : 0.f;
    ((float4*)(soft + (size_t)b * NN))[i] = o;
}

extern "C" void kernel_launch(void* const* d_in, const int* in_sizes, int n_in,
                              void* d_out, int out_size, void* d_ws, size_t ws_size,
                              hipStream_t stream) {
    (void)in_sizes; (void)n_in; (void)out_size; (void)ws_size;
    const float* x        = (const float*)d_in[0];
    const int*   true_num = (const int*)d_in[1];
    const float* V        = (const float*)d_in[2];
    const float* W        = (const float*)d_in[3];
    const float* fc_w     = (const float*)d_in[4];
    const float* fc_b     = (const float*)d_in[5];

    float* out  = (float*)d_out;
    float* cls  = out;                     // B*NCLS = 16
    float* soft = out + BB * 2;            // B*N = 32768

    float* dis   = (float*)d_ws;                 // 32768
    float* mblk  = dis + (size_t)BB * NN;        // 2048
    float* lblk  = mblk + 2048;                  // 2048
    float* qblk  = lblk + 2048;                  // 2048*16
    short* Vp    = (short*)(qblk + (size_t)2048 * 16);  // 256 KiB

    k_pack_v<<<64, 256, 0, stream>>>(V, Vp);
    k_fused<<<2048, 512, 0, stream>>>(x, true_num, Vp, W, fc_w,
                                      dis, mblk, lblk, qblk);
    k_final<<<32, 256, 0, stream>>>(dis, true_num, mblk, lblk, qblk, fc_b,
                                    soft, cls);
}